// Round 3
// baseline (728.189 us; speedup 1.0000x reference)
//
#include <hip/hip_runtime.h>
#include <math.h>
#include <stdint.h>

// ---------------------------------------------------------------------------
// GCN: 6 layers of  h' = act( segsum_dst( edge_val * (h @ W)[src] ) + b )
// dims: 512 -> 12 -> 10 -> 8 -> 6 -> 4 -> 7
//
// Round 7: layer gather rebuilt branchless.
//  - finalize persists per-bucket per-localdst offsets (offsTab); each layer
//    block builds <=320 run-aligned work items (single ld, <=10 edges) and the
//    inner loop is a fully-unrolled 10-step pipeline: all LDS reads + gathers
//    batch-issued, pad lanes clamp to last edge (L1 hit) with weight 0,
//    exactly one 12-atomic flush per item (was: masked flush ~every iter).
//  - G1/G2 feature rows padded to 64 B (stride 16 floats) -> 1 cache line per
//    gather instead of ~1.4.
//  - CSR: padded bucket layout (base=b*FCAP) -> scanA/scanB deleted, finalize
//    pad-fill deleted (layers clamp to ne). 11 dispatches total.
// ---------------------------------------------------------------------------

#define T_EDGES 12800   // edges per tile (E=3.2M -> exactly 250 tiles)
#define NB_MAX  1600    // max fine buckets (N<=102400)
#define FCAP    2560    // edge slots per 64-node bucket (mean 2048, max~2202)
#define OTSTR   72      // offsTab row stride (65 used)
#define KIT     10      // edges per work item
#define MAXIT   336     // >= floor(FCAP/KIT)+64 = 320

// ---- per-tile bucket histogram ----
__global__ __launch_bounds__(512) void hist_kernel(const int* __restrict__ dst,
                                                   int* __restrict__ ghist, int E, int NB) {
    __shared__ int h[NB_MAX];
    for (int i = threadIdx.x; i < NB; i += 512) h[i] = 0;
    __syncthreads();
    int base = blockIdx.x * T_EDGES;
    int n = min(T_EDGES, E - base);
    for (int i = threadIdx.x; i < n; i += 512)
        atomicAdd(&h[((unsigned)dst[base + i]) >> 6], 1);
    __syncthreads();
    for (int i = threadIdx.x; i < NB; i += 512)
        ghist[(size_t)blockIdx.x * NB + i] = h[i];
}

// ---- per-(tile,bucket) global offsets in padded layout + per-bucket totals ----
__global__ __launch_bounds__(256) void scanC_kernel(const int* __restrict__ ghist,
                                                    int* __restrict__ goff,
                                                    int* __restrict__ btot, int NT, int NB) {
    __shared__ int part[256];
    int b = blockIdx.x, t = threadIdx.x;
    int v = (t < NT) ? ghist[(size_t)t * NB + b] : 0;
    part[t] = v;
    __syncthreads();
    for (int off = 1; off < 256; off <<= 1) {
        int x = (t >= off) ? part[t - off] : 0;
        __syncthreads();
        part[t] += x;
        __syncthreads();
    }
    if (t < NT) goff[(size_t)t * NB + b] = b * FCAP + part[t] - v;
    if (t == 255) btot[b] = part[255];
}

// ---- scatter: LDS counting-sort per tile, run-writes to exact offsets ----
__global__ __launch_bounds__(1024) void scatter_kernel(const int* __restrict__ src,
                                                       const int* __restrict__ dst,
                                                       const float* __restrict__ val,
                                                       const int* __restrict__ ghist,
                                                       const int* __restrict__ goff,
                                                       int2* __restrict__ edges, int E, int NB) {
    __shared__ unsigned perm[T_EDGES];   // 51200 B
    __shared__ int loff[NB_MAX];         // 6400 B
    __shared__ int lcur[NB_MAX];         // 6400 B
    __shared__ int part[1024];           // 4096 B
    int tb = blockIdx.x, t = threadIdx.x;
    int base = tb * T_EDGES;
    int n = min(T_EDGES, E - base);

    int chunk = (NB + 1023) / 1024;
    int lo = t * chunk, hi = min(lo + chunk, NB);
    int s = 0;
    for (int i = lo; i < hi; i++) {
        int c = ghist[(size_t)tb * NB + i];
        loff[i] = c;
        s += c;
    }
    part[t] = s;
    __syncthreads();
    for (int off = 1; off < 1024; off <<= 1) {
        int x = (t >= off) ? part[t - off] : 0;
        __syncthreads();
        part[t] += x;
        __syncthreads();
    }
    int run = part[t] - s;
    for (int i = lo; i < hi; i++) {
        int c = loff[i];
        loff[i] = run;
        lcur[i] = run;
        run += c;
    }
    __syncthreads();

    for (int i = t; i < n; i += 1024) {
        int d = dst[base + i];
        unsigned b = ((unsigned)d) >> 6;
        int p = atomicAdd(&lcur[b], 1);
        perm[p] = (unsigned)i | (b << 14) | ((unsigned)(d & 63) << 25);
    }
    __syncthreads();

    for (int o = t; o < n; o += 1024) {
        unsigned v = perm[o];
        int li = v & 16383;
        int b  = (v >> 14) & 2047;
        int ld = v >> 25;
        int g  = goff[(size_t)tb * NB + b] + (o - loff[b]);
        edges[g] = make_int2(src[base + li] | (ld << 17), __float_as_int(val[base + li]));
    }
}

// ---- finalize: sort bucket by local dst; persist per-ld offsets + total ----
__global__ __launch_bounds__(512) void finalize_kernel(int2* __restrict__ edges,
                                                       const int* __restrict__ btot,
                                                       int* __restrict__ offsTab) {
    __shared__ int2 recs[FCAP];
    __shared__ int2 recs2[FCAP];
    __shared__ int cnt[64], offs[64], cur[64];
    int b = blockIdx.x, t = threadIdx.x;
    size_t s0 = (size_t)b * FCAP;
    int ne = min(btot[b], FCAP);
    if (t < 64) cnt[t] = 0;
    __syncthreads();
    for (int i = t; i < ne; i += 512) {
        int2 r = edges[s0 + i];
        recs[i] = r;
        atomicAdd(&cnt[(r.x >> 17) & 63], 1);
    }
    __syncthreads();
    if (t == 0) {
        int run = 0;
        for (int i = 0; i < 64; i++) { offs[i] = run; run += cnt[i]; }
    }
    __syncthreads();
    if (t < 64) cur[t] = offs[t];
    __syncthreads();
    for (int i = t; i < ne; i += 512) {
        int2 r = recs[i];
        int ld = (r.x >> 17) & 63;
        int p = atomicAdd(&cur[ld], 1);
        recs2[p] = r;
    }
    __syncthreads();
    for (int i = t; i < ne; i += 512) edges[s0 + i] = recs2[i];
    if (t < 64) offsTab[(size_t)b * OTSTR + t] = offs[t];
    if (t == 64) offsTab[(size_t)b * OTSTR + 64] = ne;
}

// ---- layer 1 dense: s1 = x @ W1, out stride 16 (64 B rows, pads zeroed) ----
__global__ __launch_bounds__(256) void dense1_kernel(const float* __restrict__ x,
                                                     const float* __restrict__ W,
                                                     float* __restrict__ out, int N) {
    __shared__ float xs[256 * 33];
    const int t    = threadIdx.x;
    const int row0 = blockIdx.x * 256;
    const int r    = row0 + t;

    float acc[12];
#pragma unroll
    for (int j = 0; j < 12; j++) acc[j] = 0.f;

    for (int tile = 0; tile < 16; ++tile) {
#pragma unroll
        for (int i = 0; i < 8; i++) {
            int idx4 = t + 256 * i;
            int flat = idx4 * 4;
            int rl   = flat >> 5;
            int c    = flat & 31;
            int rg   = row0 + rl;
            if (rg >= N) rg = N - 1;
            const float4 v = *(const float4*)(x + (size_t)rg * 512 + tile * 32 + c);
            float* p = &xs[rl * 33 + c];
            p[0] = v.x; p[1] = v.y; p[2] = v.z; p[3] = v.w;
        }
        __syncthreads();
#pragma unroll 8
        for (int kk = 0; kk < 32; ++kk) {
            float xv = xs[t * 33 + kk];
            int k = tile * 32 + kk;
#pragma unroll
            for (int j = 0; j < 12; j++) acc[j] += xv * W[k * 12 + j];
        }
        __syncthreads();
    }
    if (r < N) {
        float4* orow = (float4*)(out + (size_t)r * 16);
        orow[0] = make_float4(acc[0], acc[1], acc[2], acc[3]);
        orow[1] = make_float4(acc[4], acc[5], acc[6], acc[7]);
        orow[2] = make_float4(acc[8], acc[9], acc[10], acc[11]);
        orow[3] = make_float4(0.f, 0.f, 0.f, 0.f);
    }
}

// ---- bucket-parallel fused layer, branchless run-aligned items ----
// SV: float4-stride of input rows. ANV: float4s gathered/accumulated (<=SV).
// ACT: 0 none, 1 relu, 2 tanhshrink.  FINAL: write h as DIN floats (stride DIN).
template <int SV, int ANV, int DIN, int DOUT, int OSTR, int ACT, bool FINAL>
__global__ __launch_bounds__(256) void layer_kernel(const int2* __restrict__ edges,
                                                    const int* __restrict__ offsTab,
                                                    const float* __restrict__ s,
                                                    const float* __restrict__ bias,
                                                    const float* __restrict__ W,
                                                    float* __restrict__ out, int N) {
    constexpr int ASTR = 13;                 // padded acc stride
    __shared__ int2  ebuf[FCAP];             // 20480 B
    __shared__ float acc[64 * ASTR];         // 3328 B
    __shared__ int   offs[65];
    __shared__ int   items[MAXIT];
    __shared__ int   nitems_s;
    const int b = blockIdx.x, t = threadIdx.x;
    const int ne = offsTab[(size_t)b * OTSTR + 64];   // uniform s_load

    for (int i = t; i < 64 * ASTR; i += 256) acc[i] = 0.f;
    for (int i = t; i < ne; i += 256) ebuf[i] = edges[(size_t)b * FCAP + i];
    if (t < 65) offs[t] = offsTab[(size_t)b * OTSTR + t];
    if (t == 0) nitems_s = 0;
    __syncthreads();

    // build run-aligned work items: (ld, start, len<=KIT), single ld per item
    if (t < 64) {
        int st = offs[t];
        int c  = ((t == 63) ? ne : offs[t + 1]) - st;
        if (c > 0) {
            int ni  = (c + KIT - 1) / KIT;
            int pos = atomicAdd(&nitems_s, ni);
            for (int j = 0; j < ni; j++) {
                int len = min(KIT, c - j * KIT);
                items[pos + j] = ((st + j * KIT) << 10) | (len << 6) | t;
            }
        }
    }
    __syncthreads();

    const int nit = nitems_s;
    const float4* sv = (const float4*)s;
    for (int j = t; j < nit; j += 256) {
        int it = items[j];
        int ld    = it & 63;
        int lenm1 = ((it >> 6) & 15) - 1;
        int st    = it >> 10;
        float4 a[ANV];
#pragma unroll
        for (int v = 0; v < ANV; v++) a[v] = make_float4(0.f, 0.f, 0.f, 0.f);
#pragma unroll
        for (int k = 0; k < KIT; k++) {
            int idx = st + min(k, lenm1);          // pad lanes re-read last edge
            int2 ev = ebuf[idx];
            float w = (k <= lenm1) ? __int_as_float(ev.y) : 0.f;
            const float4* srow = sv + (size_t)(ev.x & 0x1FFFF) * SV;
#pragma unroll
            for (int v = 0; v < ANV; v++) {
                float4 xr = srow[v];
                a[v].x += w * xr.x; a[v].y += w * xr.y;
                a[v].z += w * xr.z; a[v].w += w * xr.w;
            }
        }
#pragma unroll
        for (int v = 0; v < ANV; v++) {
            atomicAdd(&acc[ld * ASTR + 4 * v + 0], a[v].x);
            atomicAdd(&acc[ld * ASTR + 4 * v + 1], a[v].y);
            atomicAdd(&acc[ld * ASTR + 4 * v + 2], a[v].z);
            atomicAdd(&acc[ld * ASTR + 4 * v + 3], a[v].w);
        }
    }
    __syncthreads();

    // epilogue: node-per-thread (t<64), bias+act, next dense, coalesced store
    if (t < 64) {
        int node = (b << 6) + t;
        if (node < N) {
            float h[DIN];
#pragma unroll
            for (int k = 0; k < DIN; k++) {
                float z = acc[t * ASTR + k] + bias[k];
                if (ACT == 1) z = fmaxf(z, 0.f);
                else if (ACT == 2) z = z - tanhf(z);
                h[k] = z;
            }
            if (FINAL) {
#pragma unroll
                for (int k = 0; k < DIN; k++) out[(size_t)node * DIN + k] = h[k];
            } else {
                float o[OSTR];
#pragma unroll
                for (int j = 0; j < OSTR; j++) o[j] = 0.f;  // zero pads
#pragma unroll
                for (int j = 0; j < DOUT; j++) {
                    float tj = 0.f;
#pragma unroll
                    for (int k = 0; k < DIN; k++) tj += h[k] * W[k * DOUT + j];
                    o[j] = tj;
                }
                float4* orow = (float4*)(out + (size_t)node * OSTR);
#pragma unroll
                for (int v = 0; v < OSTR / 4; v++)
                    orow[v] = make_float4(o[4 * v], o[4 * v + 1], o[4 * v + 2], o[4 * v + 3]);
            }
        }
    }
}

// ---------------- launcher ----------------

static inline size_t align256(size_t x) { return (x + 255) & ~(size_t)255; }

extern "C" void kernel_launch(void* const* d_in, const int* in_sizes, int n_in,
                              void* d_out, int out_size, void* d_ws, size_t ws_size,
                              hipStream_t stream) {
    const float* x        = (const float*)d_in[0];
    const float* edge_val = (const float*)d_in[1];
    const int*   edge_src = (const int*)d_in[2];
    const int*   edge_dst = (const int*)d_in[3];
    const float* W1 = (const float*)d_in[4];   const float* b1 = (const float*)d_in[5];
    const float* W2 = (const float*)d_in[6];   const float* b2 = (const float*)d_in[7];
    const float* W3 = (const float*)d_in[8];   const float* b3 = (const float*)d_in[9];
    const float* W4 = (const float*)d_in[10];  const float* b4 = (const float*)d_in[11];
    const float* W5 = (const float*)d_in[12];  const float* b5 = (const float*)d_in[13];
    const float* W6 = (const float*)d_in[14];  const float* b6 = (const float*)d_in[15];

    const int N = in_sizes[0] / 512;        // 100000
    const int E = in_sizes[1];              // 3200000
    float* out = (float*)d_out;

    const int NB = (N + 63) >> 6;           // 1563 fine buckets
    const int NT = (E + T_EDGES - 1) / T_EDGES;  // 250 tiles (<=256 required)
    const int nb = (N + 255) / 256;

    // workspace carve-up (~50 MB)
    char* w = (char*)d_ws;
    float* A       = (float*)w;  w += align256((size_t)N * 16 * sizeof(float));
    float* B       = (float*)w;  w += align256((size_t)N * 16 * sizeof(float));
    int*   ghist   = (int*)w;    w += align256((size_t)NT * NB * sizeof(int));
    int*   goff    = (int*)w;    w += align256((size_t)NT * NB * sizeof(int));
    int*   btot    = (int*)w;    w += align256((size_t)NB * sizeof(int));
    int*   offsTab = (int*)w;    w += align256((size_t)NB * OTSTR * sizeof(int));
    int2*  edges   = (int2*)w;   w += align256((size_t)NB * FCAP * sizeof(int2));

    // ---- CSR build: radix partition into strided padded buckets ----
    hist_kernel<<<NT, 512, 0, stream>>>(edge_dst, ghist, E, NB);
    scanC_kernel<<<NB, 256, 0, stream>>>(ghist, goff, btot, NT, NB);
    scatter_kernel<<<NT, 1024, 0, stream>>>(edge_src, edge_dst, edge_val, ghist, goff, edges, E, NB);
    finalize_kernel<<<NB, 512, 0, stream>>>(edges, btot, offsTab);

    // ---- dense1: s1 = x @ W1 (stride 16, 64 B-aligned rows) ----
    dense1_kernel<<<nb, 256, 0, stream>>>(x, W1, A, N);

    // ---- fused bucket-parallel gather+dense chain ----
    // G1: agg(s1,str16) -> h1=agg+b1 -> s2=h1@W2 (12->10, out stride 16)
    layer_kernel<4, 3, 12, 10, 16, 0, false><<<NB, 256, 0, stream>>>(edges, offsTab, A, b1, W2, B, N);
    // G2: agg(s2,str16) -> h2=relu -> s3=h2@W3 (10->8, out stride 8)
    layer_kernel<4, 3, 10, 8, 8, 1, false><<<NB, 256, 0, stream>>>(edges, offsTab, B, b2, W3, A, N);
    // G3: agg(s3,str8) -> h3=ts -> s4=h3@W4 (8->6, out stride 8)
    layer_kernel<2, 2, 8, 6, 8, 2, false><<<NB, 256, 0, stream>>>(edges, offsTab, A, b3, W4, B, N);
    // G4: agg(s4,str8) -> h4=ts -> s5=h4@W5 (6->4, out stride 4)
    layer_kernel<2, 2, 6, 4, 4, 2, false><<<NB, 256, 0, stream>>>(edges, offsTab, B, b4, W5, A, N);
    // G5: agg(s5,str4) -> h5=agg+b5 -> s6=h5@W6 (4->7, out stride 8)
    layer_kernel<1, 1, 4, 7, 8, 0, false><<<NB, 256, 0, stream>>>(edges, offsTab, A, b5, W6, B, N);
    // G6: out = agg6 + b6 (7 floats, exact layout)
    layer_kernel<2, 2, 7, 7, 8, 0, true><<<NB, 256, 0, stream>>>(edges, offsTab, B, b6, (const float*)nullptr, out, N);
}